// Round 7
// baseline (433.912 us; speedup 1.0000x reference)
//
#include <hip/hip_runtime.h>

// SSIM_13443247637111 — round 7: occupancy-first H-ring design.
//  - 256-thr blocks, SSTEP=16, RING=27 -> LDS 41.5 KB -> 3 blocks/CU
//    = 12 waves/CU = 3 waves/SIMD (the round-5/6 fix: LDS/block is the
//    occupancy lever; 1-wave blocks gave only 1.25 waves/SIMD).
//  - H phase: 256 tasks, 4 px each (20-float window), fields -> ring.
//  - V phase: 128 tasks, 2 rows x 4 cols, streamed per-field accumulation.
//  - Rotate-swizzle (quad+slot)&15 keeps both patterns bank-balanced.

#define IMH 512
#define IMW 512
#define NCH 3
#define SW 64
#define SH 64
#define SSTEP 16
#define NIT (SH / SSTEP)       // 4
#define RING 27
#define NBLK 3072

__device__ __forceinline__ float4 ld4(const float* p) { return *(const float4*)p; }
__device__ __forceinline__ void st4(float* p, float4 v) { *(float4*)p = v; }

// LDS index: field f, row slot, logical quad qo (0..15), rotate-swizzled
__device__ __forceinline__ int hbi(int f, int slot, int qo) {
    return ((f * RING + slot) << 6) + (((qo + slot) & 15) << 2);
}

__global__ __launch_bounds__(256) void ssim_main(
    const float* __restrict__ img1, const float* __restrict__ img2,
    const float* __restrict__ match,
    float* __restrict__ wsn, float* __restrict__ wsd,
    double* __restrict__ acc, int use_partials)
{
    __shared__ __align__(16) float hb[6 * RING * 64];   // 41472 B
    __shared__ float redn[4], redd[4];

    const int tid = threadIdx.x;              // 0..255
    const int bc = blockIdx.z;
    const int b = bc / NCH;
    const int c = bc - b * NCH;
    const int ystart = blockIdx.y * SH;
    const int bx0 = blockIdx.x * SW;

    const float* p1 = img1 + (size_t)(b * NCH + c) * (IMH * IMW);
    const float* p2 = img2 + (size_t)(b * NCH + c) * (IMH * IMW);
    const float* pm = match + (size_t)b * (IMH * IMW);

    float g[11];
    {
        float s = 0.0f;
        #pragma unroll
        for (int i = 0; i < 11; ++i) {
            float d = (float)(i - 5);
            g[i] = expf(-(d * d) / 4.5f);
            s += g[i];
        }
        #pragma unroll
        for (int i = 0; i < 11; ++i) g[i] /= s;
    }

    float num = 0.0f, den = 0.0f;

    // ---- H phase: rows [h0, h0+hn) strip-relative, 16 tasks/row ----
    // task = (row, quad qt): produce 4 outputs at x = bx0+4qt .. +3 from a
    // 20-float window starting at x = bx0 + 4qt - 8.
    auto phaseH = [&](int h0, int hn) {
        for (int t = tid; t < hn * 16; t += 256) {
            int r = t >> 4, qt = t & 15;
            int ra = h0 + r;
            int gy = ystart + ra;
            int slot = (ra + 5) % RING;
            bool rok = ((unsigned)gy < IMH);
            int rowoff = (rok ? gy : 0) * IMW;
            int gxb = bx0 + 4 * qt - 8;          // global x of window[0]

            float X1[20], X2[20], P[20];
            float4 O;

            auto load20 = [&](const float* __restrict__ src, float* dst) {
                #pragma unroll
                for (int j = 0; j < 5; ++j) {
                    int gx = gxb + 4 * j;
                    if (rok && gx >= 0 && gx <= IMW - 4) {
                        float4 v = ld4(src + rowoff + gx);
                        dst[4*j] = v.x; dst[4*j+1] = v.y;
                        dst[4*j+2] = v.z; dst[4*j+3] = v.w;
                    } else {
                        #pragma unroll
                        for (int e = 0; e < 4; ++e) {
                            int gx2 = gx + e;
                            bool ok = rok && ((unsigned)gx2 < IMW);
                            float v = src[ok ? (rowoff + gx2) : 0];
                            dst[4*j+e] = ok ? v : 0.0f;
                        }
                    }
                }
            };
            auto convO = [&](const float* W) {
                float o[4];
                #pragma unroll
                for (int cc = 0; cc < 4; ++cc) {
                    float s = 0.0f;
                    #pragma unroll
                    for (int k = 0; k < 11; ++k) s = fmaf(g[k], W[cc + 3 + k], s);
                    o[cc] = s;
                }
                O = make_float4(o[0], o[1], o[2], o[3]);
            };

            load20(p1, X1);
            load20(p2, X2);
            convO(X1); st4(&hb[hbi(0, slot, qt)], O);
            convO(X2); st4(&hb[hbi(1, slot, qt)], O);
            #pragma unroll
            for (int j = 0; j < 20; ++j) P[j] = X1[j] * X2[j];
            convO(P);  st4(&hb[hbi(4, slot, qt)], O);
            #pragma unroll
            for (int j = 0; j < 20; ++j) P[j] = X1[j] * X1[j];
            convO(P);  st4(&hb[hbi(2, slot, qt)], O);
            #pragma unroll
            for (int j = 0; j < 20; ++j) P[j] = X2[j] * X2[j];
            convO(P);  st4(&hb[hbi(3, slot, qt)], O);
            load20(pm, X1);                       // reuse X1 for match
            {
                float o[4];
                #pragma unroll
                for (int cc = 0; cc < 4; ++cc) {
                    float s = 0.0f;
                    #pragma unroll
                    for (int k = 0; k < 11; ++k) s += X1[cc + 3 + k];
                    o[cc] = s;
                }
                O = make_float4(o[0], o[1], o[2], o[3]);
            }
            st4(&hb[hbi(5, slot, qt)], O);
        }
    };

    // prologue: rows [-5, 5)
    phaseH(-5, 10);

    for (int i = 0; i < NIT; ++i) {
        // produce H-field rows [16i+5, 16i+21)
        phaseH(SSTEP * i + 5, SSTEP);
        __syncthreads();   // B1: ring writes visible

        // ---- V phase: 128 tasks = 16 quads x 8 row-pairs ----
        if (tid < 128) {
            int qd = tid & 15, pj = tid >> 4;      // pj 0..7
            int r0 = SSTEP * i + 2 * pj;           // output rows r0, r0+1
            int s0 = r0 % RING;                    // slot of row r0-5

            int off[12];
            {
                int s = s0;
                #pragma unroll
                for (int k = 0; k < 12; ++k) {
                    off[k] = (s << 6) + (((qd + s) & 15) << 2);
                    ++s; if (s == RING) s = 0;
                }
            }

            float res[6][8];
            #pragma unroll
            for (int f = 0; f < 6; ++f) {
                const float* base = hb + f * (RING * 64);
                float a0x = 0.f, a0y = 0.f, a0z = 0.f, a0w = 0.f;
                float a1x = 0.f, a1y = 0.f, a1z = 0.f, a1w = 0.f;
                #pragma unroll
                for (int k = 0; k < 12; ++k) {     // rows r0-5 .. r0+6
                    float4 v = ld4(base + off[k]);
                    if (f < 5) {
                        if (k < 11) {
                            float w = g[k];
                            a0x = fmaf(w, v.x, a0x); a0y = fmaf(w, v.y, a0y);
                            a0z = fmaf(w, v.z, a0z); a0w = fmaf(w, v.w, a0w);
                        }
                        if (k > 0) {
                            float w = g[k - 1];
                            a1x = fmaf(w, v.x, a1x); a1y = fmaf(w, v.y, a1y);
                            a1z = fmaf(w, v.z, a1z); a1w = fmaf(w, v.w, a1w);
                        }
                    } else {
                        if (k < 11) { a0x += v.x; a0y += v.y; a0z += v.z; a0w += v.w; }
                        if (k > 0)  { a1x += v.x; a1y += v.y; a1z += v.z; a1w += v.w; }
                    }
                }
                res[f][0] = a0x; res[f][1] = a0y; res[f][2] = a0z; res[f][3] = a0w;
                res[f][4] = a1x; res[f][5] = a1y; res[f][6] = a1z; res[f][7] = a1w;
            }

            #pragma unroll
            for (int j = 0; j < 8; ++j) {
                float mu1 = res[0][j], mu2 = res[1][j];
                float mu1s = mu1 * mu1, mu2s = mu2 * mu2, mu12 = mu1 * mu2;
                float s11 = res[2][j] - mu1s;
                float s22 = res[3][j] - mu2s;
                float s12 = res[4][j] - mu12;
                float ssim = ((2.0f * mu12 + 1e-4f) * (2.0f * s12 + 9e-4f)) /
                             ((mu1s + mu2s + 1e-4f) * (s11 + s22 + 9e-4f));
                float m = fmaf(res[5][j], (1.0f / 121.0f), 1e-7f);
                float mask = (m > 0.5f) ? (1.0f + 1e-7f) : 1e-7f;
                num = fmaf(1.0f - ssim, mask, num);
                den += mask;
            }
        }
        __syncthreads();   // B2: V reads done before next H overwrites ring
    }

    // ---- block reduction ----
    for (int off = 32; off > 0; off >>= 1) {
        num += __shfl_down(num, off);
        den += __shfl_down(den, off);
    }
    int wave = tid >> 6;
    int lane = tid & 63;
    if (lane == 0) { redn[wave] = num; redd[wave] = den; }
    __syncthreads();
    if (tid == 0) {
        float n = redn[0] + redn[1] + redn[2] + redn[3];
        float d = redd[0] + redd[1] + redd[2] + redd[3];
        if (use_partials) {
            int bid = (blockIdx.z * gridDim.y + blockIdx.y) * gridDim.x + blockIdx.x;
            wsn[bid] = n;
            wsd[bid] = d;
        } else {
            atomicAdd(&acc[0], (double)n);
            if (c == 0) atomicAdd(&acc[1], (double)d);
        }
    }
}

__global__ void finalize_partials(const float* __restrict__ wsn,
                                  const float* __restrict__ wsd,
                                  float* __restrict__ out) {
    __shared__ double rn[4], rd[4];
    int tid = threadIdx.x;
    double num = 0.0, den = 0.0;
    for (int i = tid; i < NBLK; i += 256) {
        num += (double)wsn[i];
        int z = i >> 6;            // 8x8 = 64 blocks per z-slice
        if (z % NCH == 0) den += (double)wsd[i];
    }
    for (int off = 32; off > 0; off >>= 1) {
        num += __shfl_down(num, off);
        den += __shfl_down(den, off);
    }
    int wave = tid >> 6, lane = tid & 63;
    if (lane == 0) { rn[wave] = num; rd[wave] = den; }
    __syncthreads();
    if (tid == 0) {
        num = rn[0] + rn[1] + rn[2] + rn[3];
        den = rd[0] + rd[1] + rd[2] + rd[3];
        out[0] = (float)(num / den / 3.0);
    }
}

__global__ void init_acc(double* acc) { acc[0] = 0.0; acc[1] = 0.0; }

__global__ void finalize_atomic(const double* __restrict__ acc,
                                float* __restrict__ out) {
    out[0] = (float)(acc[0] / acc[1] / 3.0);
}

extern "C" void kernel_launch(void* const* d_in, const int* in_sizes, int n_in,
                              void* d_out, int out_size, void* d_ws, size_t ws_size,
                              hipStream_t stream) {
    const float* img1  = (const float*)d_in[0];
    const float* img2  = (const float*)d_in[1];
    const float* match = (const float*)d_in[2];
    float* out = (float*)d_out;

    dim3 grid(IMW / SW, IMH / SH, 16 * NCH);   // 8 x 8 x 48 = 3072
    dim3 block(256, 1, 1);

    int use_partials = (ws_size >= (size_t)(2 * NBLK * sizeof(float))) ? 1 : 0;
    if (use_partials) {
        float* wsn = (float*)d_ws;
        float* wsd = wsn + NBLK;
        ssim_main<<<grid, block, 0, stream>>>(img1, img2, match, wsn, wsd,
                                              (double*)nullptr, 1);
        finalize_partials<<<1, 256, 0, stream>>>(wsn, wsd, out);
    } else {
        double* acc = (double*)d_ws;
        init_acc<<<1, 1, 0, stream>>>(acc);
        ssim_main<<<grid, block, 0, stream>>>(img1, img2, match,
                                              (float*)nullptr, (float*)nullptr,
                                              acc, 0);
        finalize_atomic<<<1, 1, 0, stream>>>(acc, out);
    }
}